// Round 1
// baseline (6845.198 us; speedup 1.0000x reference)
//
#include <hip/hip_runtime.h>

// ---------------------------------------------------------------------------
// GCN: 3 layers of  h = norm_dst * SpMM(norm_src * (h @ W)) + h @ L (+ b)
// fp32 everywhere (round 0: correctness-first).
// ---------------------------------------------------------------------------

__global__ void deg_kernel(const int* __restrict__ src, const int* __restrict__ dst,
                           float* __restrict__ deg_out, float* __restrict__ deg_in, int E) {
    int i = blockIdx.x * blockDim.x + threadIdx.x;
    if (i < E) {
        atomicAdd(&deg_out[src[i]], 1.0f);
        atomicAdd(&deg_in[dst[i]], 1.0f);
    }
}

__global__ void norm_kernel(float* __restrict__ v, int n) {
    int i = blockIdx.x * blockDim.x + threadIdx.x;
    if (i < n) v[i] = rsqrtf(fmaxf(v[i], 1.0f));
}

// C[M x NC] = (SCALE_ROW ? rowscale[r] : 1) * (A[M x 128] @ B[128 x NC]) (+ bias[c])
template<int NC, bool SCALE_ROW, bool ADD_BIAS>
__global__ __launch_bounds__(256) void gemm_kernel(
    const float* __restrict__ A,
    const float* __restrict__ Bw,
    const float* __restrict__ rowscale,
    const float* __restrict__ bias,
    float* __restrict__ Cout,
    int M)
{
    constexpr int K  = 128;
    constexpr int KB = 32;
    constexpr int BM = 64;
    constexpr int TCOLS = (NC == 128) ? 16 : 8;   // threads along cols
    constexpr int MN    = NC / TCOLS;             // 8 (NC=128) or 5 (NC=40)
    constexpr int TROWS = 256 / TCOLS;            // 16 or 32
    constexpr int MM    = BM / TROWS;             // 4 or 2
    constexpr int APAD  = 4;                      // stride 36: 2-way bank alias (free)

    __shared__ float As[BM][KB + APAD];
    __shared__ float Bs[KB][NC];

    const int tid  = threadIdx.x;
    const int tc   = tid % TCOLS;
    const int tr   = tid / TCOLS;
    const int row0 = blockIdx.x * BM;

    float acc[MM][MN];
#pragma unroll
    for (int i = 0; i < MM; ++i)
#pragma unroll
        for (int j = 0; j < MN; ++j) acc[i][j] = 0.0f;

    for (int k0 = 0; k0 < K; k0 += KB) {
        // stage A tile (BM x KB), guarded rows -> 0
        for (int i = tid; i < BM * (KB / 4); i += 256) {
            int r  = i / (KB / 4);
            int c4 = i % (KB / 4);
            int gr = row0 + r;
            float4 v = make_float4(0.f, 0.f, 0.f, 0.f);
            if (gr < M)
                v = *reinterpret_cast<const float4*>(&A[(size_t)gr * K + k0 + c4 * 4]);
            As[r][c4 * 4 + 0] = v.x;
            As[r][c4 * 4 + 1] = v.y;
            As[r][c4 * 4 + 2] = v.z;
            As[r][c4 * 4 + 3] = v.w;
        }
        // stage B tile (KB x NC)
        for (int i = tid; i < KB * (NC / 4); i += 256) {
            int r  = i / (NC / 4);
            int c4 = i % (NC / 4);
            float4 v = *reinterpret_cast<const float4*>(&Bw[(size_t)(k0 + r) * NC + c4 * 4]);
            *reinterpret_cast<float4*>(&Bs[r][c4 * 4]) = v;
        }
        __syncthreads();
#pragma unroll
        for (int kk = 0; kk < KB; ++kk) {
            float a[MM], b[MN];
#pragma unroll
            for (int i = 0; i < MM; ++i) a[i] = As[tr * MM + i][kk];
#pragma unroll
            for (int j = 0; j < MN; ++j) b[j] = Bs[kk][tc * MN + j];
#pragma unroll
            for (int i = 0; i < MM; ++i)
#pragma unroll
                for (int j = 0; j < MN; ++j)
                    acc[i][j] += a[i] * b[j];
        }
        __syncthreads();
    }

#pragma unroll
    for (int i = 0; i < MM; ++i) {
        int r = row0 + tr * MM + i;
        if (r >= M) continue;
        float s = SCALE_ROW ? rowscale[r] : 1.0f;
#pragma unroll
        for (int j = 0; j < MN; ++j) {
            int c = tc * MN + j;
            float v = acc[i][j];
            if (SCALE_ROW) v *= s;
            if (ADD_BIAS)  v += bias[c];
            Cout[(size_t)r * NC + c] = v;
        }
    }
}

// OUT[dst[e]] += P[src[e]] * norm_dst[dst[e]]   (OUT pre-filled with residual)
template<int NC>
__global__ __launch_bounds__(256) void scatter_kernel(
    const float* __restrict__ P,
    const int* __restrict__ src, const int* __restrict__ dst,
    const float* __restrict__ norm_dst,
    float* __restrict__ OUT, int E)
{
    constexpr int C4 = NC / 4;
    int gid = blockIdx.x * blockDim.x + threadIdx.x;
    int total = E * C4;
    if (gid >= total) return;
    int e  = gid / C4;
    int c4 = gid - e * C4;
    int s = src[e];
    int d = dst[e];
    float nd = norm_dst[d];
    float4 p = *reinterpret_cast<const float4*>(&P[(size_t)s * NC + c4 * 4]);
    float* o = &OUT[(size_t)d * NC + c4 * 4];
    atomicAdd(o + 0, p.x * nd);
    atomicAdd(o + 1, p.y * nd);
    atomicAdd(o + 2, p.z * nd);
    atomicAdd(o + 3, p.w * nd);
}

extern "C" void kernel_launch(void* const* d_in, const int* in_sizes, int n_in,
                              void* d_out, int out_size, void* d_ws, size_t ws_size,
                              hipStream_t stream) {
    const float* feat = (const float*)d_in[0];
    const int*   src  = (const int*)d_in[1];
    const int*   dst  = (const int*)d_in[2];
    const float* W0   = (const float*)d_in[3];
    const float* W1   = (const float*)d_in[4];
    const float* W2   = (const float*)d_in[5];
    const float* b2   = (const float*)d_in[6];
    const float* L0   = (const float*)d_in[7];
    const float* L1   = (const float*)d_in[8];
    const float* L2   = (const float*)d_in[9];
    float* out = (float*)d_out;

    const int E = in_sizes[1];
    const int N = in_sizes[0] / 128;
    constexpr int H = 128;

    float* ws       = (float*)d_ws;
    float* norm_src = ws;                       // N  (deg_out -> rsqrt)
    float* norm_dst = ws + N;                   // N  (deg_in  -> rsqrt)
    float* bufA     = ws + 2 * (size_t)N;       // N*H
    float* bufB     = bufA + (size_t)N * H;     // N*H
    float* bufC     = bufB + (size_t)N * H;     // N*H

    // degrees -> norms
    hipMemsetAsync(norm_src, 0, 2 * (size_t)N * sizeof(float), stream);
    deg_kernel<<<(E + 255) / 256, 256, 0, stream>>>(src, dst, norm_src, norm_dst, E);
    norm_kernel<<<(2 * N + 255) / 256, 256, 0, stream>>>(norm_src, 2 * N);

    const int gblocks = (N + 63) / 64;

    // layer 1: h1 = scatter(norm_src*(feat@W0)) + feat@L0        -> bufA
    gemm_kernel<128, true,  false><<<gblocks, 256, 0, stream>>>(feat, W0, norm_src, nullptr, bufB, N);
    gemm_kernel<128, false, false><<<gblocks, 256, 0, stream>>>(feat, L0, nullptr, nullptr, bufA, N);
    scatter_kernel<128><<<((size_t)E * 32 + 255) / 256, 256, 0, stream>>>(bufB, src, dst, norm_dst, bufA, E);

    // layer 2: h2 = scatter(norm_src*(h1@W1)) + h1@L1            -> bufC
    gemm_kernel<128, true,  false><<<gblocks, 256, 0, stream>>>(bufA, W1, norm_src, nullptr, bufB, N);
    gemm_kernel<128, false, false><<<gblocks, 256, 0, stream>>>(bufA, L1, nullptr, nullptr, bufC, N);
    scatter_kernel<128><<<((size_t)E * 32 + 255) / 256, 256, 0, stream>>>(bufB, src, dst, norm_dst, bufC, E);

    // layer 3: out = scatter(norm_src*(h2@W2)) + h2@L2 + b2      -> d_out
    gemm_kernel<40, true,  false><<<gblocks, 256, 0, stream>>>(bufC, W2, norm_src, nullptr, bufB, N);
    gemm_kernel<40, false, true ><<<gblocks, 256, 0, stream>>>(bufC, L2, nullptr, b2, out, N);
    scatter_kernel<40><<<((size_t)E * 10 + 255) / 256, 256, 0, stream>>>(bufB, src, dst, norm_dst, out, E);
}

// Round 2
// 1057.162 us; speedup vs baseline: 6.4751x; 6.4751x over previous
//
#include <hip/hip_runtime.h>

// ---------------------------------------------------------------------------
// GCN: 3 layers of  h = norm_dst * SpMM(norm_src * (h @ W)) + h @ L (+ b)
// Round 1: replace atomic scatter with on-device CSR + pull-gather aggregation.
// ---------------------------------------------------------------------------

// int in/out-degree histogram
__global__ void deg_kernel(const int* __restrict__ src, const int* __restrict__ dst,
                           int* __restrict__ cnt_out, int* __restrict__ cnt_in, int E) {
    int i = blockIdx.x * blockDim.x + threadIdx.x;
    if (i < E) {
        atomicAdd(&cnt_out[src[i]], 1);
        atomicAdd(&cnt_in[dst[i]], 1);
    }
}

// norm[i] = rsqrt(max(cnt[i],1))
__global__ void norm_kernel(const int* __restrict__ cnt, float* __restrict__ norm, int n) {
    int i = blockIdx.x * blockDim.x + threadIdx.x;
    if (i < n) norm[i] = rsqrtf((float)max(cnt[i], 1));
}

// single-workgroup chunked exclusive scan: row_ptr[0..N] from cnt[0..N)
__global__ __launch_bounds__(1024) void scan_kernel(const int* __restrict__ cnt,
                                                    int* __restrict__ row_ptr, int N) {
    __shared__ int sm[1024];
    __shared__ int carry_s;
    const int tid = threadIdx.x;
    if (tid == 0) carry_s = 0;
    __syncthreads();
    for (int base = 0; base < N; base += 4096) {
        int carry = carry_s;
        int idx = base + tid * 4;
        int v0 = (idx + 0 < N) ? cnt[idx + 0] : 0;
        int v1 = (idx + 1 < N) ? cnt[idx + 1] : 0;
        int v2 = (idx + 2 < N) ? cnt[idx + 2] : 0;
        int v3 = (idx + 3 < N) ? cnt[idx + 3] : 0;
        int s0 = v0, s1 = s0 + v1, s2 = s1 + v2, s3 = s2 + v3;  // local inclusive
        sm[tid] = s3;
        __syncthreads();
#pragma unroll
        for (int off = 1; off < 1024; off <<= 1) {
            int t = (tid >= off) ? sm[tid - off] : 0;
            __syncthreads();
            sm[tid] += t;
            __syncthreads();
        }
        int incl = sm[tid];          // inclusive over thread-sums
        int excl = incl - s3;        // exclusive base for this thread's 4 elems
        if (idx + 0 < N) row_ptr[idx + 0] = carry + excl;
        if (idx + 1 < N) row_ptr[idx + 1] = carry + excl + s0;
        if (idx + 2 < N) row_ptr[idx + 2] = carry + excl + s1;
        if (idx + 3 < N) row_ptr[idx + 3] = carry + excl + s2;
        __syncthreads();
        if (tid == 1023) carry_s = carry + incl;  // chunk total
        __syncthreads();
    }
    if (tid == 0) row_ptr[N] = carry_s;
}

// place each edge's src into its dst's CSR segment
__global__ void fill_kernel(const int* __restrict__ src, const int* __restrict__ dst,
                            const int* __restrict__ row_ptr, int* __restrict__ cursor,
                            int* __restrict__ col, int E) {
    int i = blockIdx.x * blockDim.x + threadIdx.x;
    if (i < E) {
        int d = dst[i];
        int pos = row_ptr[d] + atomicAdd(&cursor[d], 1);
        col[pos] = src[i];
    }
}

// OUT[d] = OUT[d] + norm_dst[d] * sum_{j in row d} Pw[col[j]]   (in-place over residual)
// NC=128: 128 threads per node (2 nodes / 256-block). NC=40: 64 threads per node, 40 active.
template<int NC>
__global__ __launch_bounds__(256) void agg_kernel(
    const float* __restrict__ Pw,
    const int* __restrict__ row_ptr, const int* __restrict__ col,
    const float* __restrict__ norm_dst,
    float* __restrict__ OUT, int N)
{
    constexpr int TPN = (NC == 128) ? 128 : 64;   // threads per node
    constexpr int NPB = 256 / TPN;                // nodes per block
    const int tid  = threadIdx.x;
    const int ln   = tid / TPN;
    const int c    = tid % TPN;
    const int node = blockIdx.x * NPB + ln;
    if (node >= N) return;
    if (NC != 128 && c >= NC) return;

    const int b = row_ptr[node];
    const int e = row_ptr[node + 1];
    float acc = 0.0f;
    int j = b;
    for (; j + 1 < e; j += 2) {
        int s0 = col[j], s1 = col[j + 1];
        acc += Pw[(size_t)s0 * NC + c];
        acc += Pw[(size_t)s1 * NC + c];
    }
    if (j < e) acc += Pw[(size_t)col[j] * NC + c];

    size_t o = (size_t)node * NC + c;
    OUT[o] = OUT[o] + norm_dst[node] * acc;
}

// C[M x NC] = (SCALE_ROW ? rowscale[r] : 1) * (A[M x 128] @ B[128 x NC]) (+ bias[c])
template<int NC, bool SCALE_ROW, bool ADD_BIAS>
__global__ __launch_bounds__(256) void gemm_kernel(
    const float* __restrict__ A,
    const float* __restrict__ Bw,
    const float* __restrict__ rowscale,
    const float* __restrict__ bias,
    float* __restrict__ Cout,
    int M)
{
    constexpr int K  = 128;
    constexpr int KB = 32;
    constexpr int BM = 64;
    constexpr int TCOLS = (NC == 128) ? 16 : 8;
    constexpr int MN    = NC / TCOLS;
    constexpr int TROWS = 256 / TCOLS;
    constexpr int MM    = BM / TROWS;
    constexpr int APAD  = 4;

    __shared__ float As[BM][KB + APAD];
    __shared__ float Bs[KB][NC];

    const int tid  = threadIdx.x;
    const int tc   = tid % TCOLS;
    const int tr   = tid / TCOLS;
    const int row0 = blockIdx.x * BM;

    float acc[MM][MN];
#pragma unroll
    for (int i = 0; i < MM; ++i)
#pragma unroll
        for (int j = 0; j < MN; ++j) acc[i][j] = 0.0f;

    for (int k0 = 0; k0 < K; k0 += KB) {
        for (int i = tid; i < BM * (KB / 4); i += 256) {
            int r  = i / (KB / 4);
            int c4 = i % (KB / 4);
            int gr = row0 + r;
            float4 v = make_float4(0.f, 0.f, 0.f, 0.f);
            if (gr < M)
                v = *reinterpret_cast<const float4*>(&A[(size_t)gr * K + k0 + c4 * 4]);
            As[r][c4 * 4 + 0] = v.x;
            As[r][c4 * 4 + 1] = v.y;
            As[r][c4 * 4 + 2] = v.z;
            As[r][c4 * 4 + 3] = v.w;
        }
        for (int i = tid; i < KB * (NC / 4); i += 256) {
            int r  = i / (NC / 4);
            int c4 = i % (NC / 4);
            float4 v = *reinterpret_cast<const float4*>(&Bw[(size_t)(k0 + r) * NC + c4 * 4]);
            *reinterpret_cast<float4*>(&Bs[r][c4 * 4]) = v;
        }
        __syncthreads();
#pragma unroll
        for (int kk = 0; kk < KB; ++kk) {
            float a[MM], b[MN];
#pragma unroll
            for (int i = 0; i < MM; ++i) a[i] = As[tr * MM + i][kk];
#pragma unroll
            for (int j = 0; j < MN; ++j) b[j] = Bs[kk][tc * MN + j];
#pragma unroll
            for (int i = 0; i < MM; ++i)
#pragma unroll
                for (int j = 0; j < MN; ++j)
                    acc[i][j] += a[i] * b[j];
        }
        __syncthreads();
    }

#pragma unroll
    for (int i = 0; i < MM; ++i) {
        int r = row0 + tr * MM + i;
        if (r >= M) continue;
        float s = SCALE_ROW ? rowscale[r] : 1.0f;
#pragma unroll
        for (int j = 0; j < MN; ++j) {
            int c = tc * MN + j;
            float v = acc[i][j];
            if (SCALE_ROW) v *= s;
            if (ADD_BIAS)  v += bias[c];
            Cout[(size_t)r * NC + c] = v;
        }
    }
}

extern "C" void kernel_launch(void* const* d_in, const int* in_sizes, int n_in,
                              void* d_out, int out_size, void* d_ws, size_t ws_size,
                              hipStream_t stream) {
    const float* feat = (const float*)d_in[0];
    const int*   src  = (const int*)d_in[1];
    const int*   dst  = (const int*)d_in[2];
    const float* W0   = (const float*)d_in[3];
    const float* W1   = (const float*)d_in[4];
    const float* W2   = (const float*)d_in[5];
    const float* b2   = (const float*)d_in[6];
    const float* L0   = (const float*)d_in[7];
    const float* L1   = (const float*)d_in[8];
    const float* L2   = (const float*)d_in[9];
    float* out = (float*)d_out;

    const int E = in_sizes[1];
    const int N = in_sizes[0] / 128;
    constexpr int H = 128;

    float* ws       = (float*)d_ws;
    float* norm_src = ws;                         // N
    float* norm_dst = ws + N;                     // N
    float* bufA     = ws + 2 * (size_t)N;         // N*H
    float* bufB     = bufA + (size_t)N * H;       // N*H  (Pw)
    float* bufC     = bufB + (size_t)N * H;       // N*H  (residual -> h_next, in place)
    int*   iws      = (int*)(bufC + (size_t)N * H);
    int*   cnt_out  = iws;                        // N
    int*   cnt_in   = iws + N;                    // N
    int*   cursor   = iws + 2 * (size_t)N;        // N
    int*   row_ptr  = iws + 3 * (size_t)N;        // N+1
    int*   col      = iws + 3 * (size_t)N + N + 1;// E

    // ---- graph preprocessing (every call; deterministic work) ----
    hipMemsetAsync(cnt_out, 0, 3 * (size_t)N * sizeof(int), stream);  // cnt_out,cnt_in,cursor
    deg_kernel<<<(E + 255) / 256, 256, 0, stream>>>(src, dst, cnt_out, cnt_in, E);
    norm_kernel<<<(2 * N + 255) / 256, 256, 0, stream>>>(cnt_out, norm_src, 2 * N);
    scan_kernel<<<1, 1024, 0, stream>>>(cnt_in, row_ptr, N);
    fill_kernel<<<(E + 255) / 256, 256, 0, stream>>>(src, dst, row_ptr, cursor, col, E);

    const int gblocks = (N + 63) / 64;

    // layer 1: h1 = agg(norm_src*(feat@W0)) + feat@L0          -> bufC
    gemm_kernel<128, true,  false><<<gblocks, 256, 0, stream>>>(feat, W0, norm_src, nullptr, bufB, N);
    gemm_kernel<128, false, false><<<gblocks, 256, 0, stream>>>(feat, L0, nullptr, nullptr, bufC, N);
    agg_kernel<128><<<(N + 1) / 2, 256, 0, stream>>>(bufB, row_ptr, col, norm_dst, bufC, N);

    // layer 2: h2 = agg(norm_src*(h1@W1)) + h1@L1              -> bufA
    gemm_kernel<128, true,  false><<<gblocks, 256, 0, stream>>>(bufC, W1, norm_src, nullptr, bufB, N);
    gemm_kernel<128, false, false><<<gblocks, 256, 0, stream>>>(bufC, L1, nullptr, nullptr, bufA, N);
    agg_kernel<128><<<(N + 1) / 2, 256, 0, stream>>>(bufB, row_ptr, col, norm_dst, bufA, N);

    // layer 3: out = agg(norm_src*(h2@W2)) + h2@L2 + b2        -> d_out
    gemm_kernel<40, true,  false><<<gblocks, 256, 0, stream>>>(bufA, W2, norm_src, nullptr, bufB, N);
    gemm_kernel<40, false, true ><<<gblocks, 256, 0, stream>>>(bufA, L2, nullptr, b2, out, N);
    agg_kernel<40><<<(N + 3) / 4, 256, 0, stream>>>(bufB, row_ptr, col, norm_dst, out, N);
}

// Round 3
// 818.328 us; speedup vs baseline: 8.3649x; 1.2919x over previous
//
#include <hip/hip_runtime.h>

// ---------------------------------------------------------------------------
// GCN, round 3: bf16 MFMA fused GEMMs ([W|L] in one pass) + bf16 CSR gather.
// h = agg(norm_src*(h@W)) + h@L  per layer; all node features bf16, acc fp32.
// ---------------------------------------------------------------------------

using frag  = __attribute__((ext_vector_type(8))) short;   // 8 bf16
using f32x4 = __attribute__((ext_vector_type(4))) float;

static __device__ __forceinline__ short f2bf(float f) {
    union { float f; unsigned u; } x; x.f = f;
    unsigned r = x.u + 0x7FFF + ((x.u >> 16) & 1);         // RNE
    return (short)(r >> 16);
}
static __device__ __forceinline__ float bf2f(unsigned short u) {
    union { unsigned u; float f; } x; x.u = ((unsigned)u) << 16;
    return x.f;
}
static __device__ __forceinline__ float bflo(unsigned u) {
    union { unsigned u; float f; } x; x.u = u << 16; return x.f;
}
static __device__ __forceinline__ float bfhi(unsigned u) {
    union { unsigned u; float f; } x; x.u = u & 0xffff0000u; return x.f;
}
static __device__ __forceinline__ unsigned pack2(float a, float b) {
    return (unsigned)(unsigned short)f2bf(a) | ((unsigned)(unsigned short)f2bf(b) << 16);
}

// ---- graph preprocessing ---------------------------------------------------

__global__ void deg_kernel(const int* __restrict__ src, const int* __restrict__ dst,
                           int* __restrict__ cnt_out, int* __restrict__ cnt_in, int E) {
    int i = blockIdx.x * blockDim.x + threadIdx.x;
    if (i < E) {
        atomicAdd(&cnt_out[src[i]], 1);
        atomicAdd(&cnt_in[dst[i]], 1);
    }
}

__global__ void norm_kernel(const int* __restrict__ cnt, float* __restrict__ norm, int n) {
    int i = blockIdx.x * blockDim.x + threadIdx.x;
    if (i < n) norm[i] = rsqrtf((float)max(cnt[i], 1));
}

// 1024-thread chunked exclusive scan with shuffle (few barriers)
__global__ __launch_bounds__(1024) void scan_kernel(const int* __restrict__ cnt,
                                                    int* __restrict__ rp, int N) {
    __shared__ int wsum[16];
    __shared__ int carry_s;
    const int tid = threadIdx.x;
    const int lane = tid & 63, wave = tid >> 6;
    if (tid == 0) carry_s = 0;
    __syncthreads();
    const int CH = 8192;
    for (int base = 0; base < N; base += CH) {
        int idx = base + tid * 8;
        int v[8], s[8];
#pragma unroll
        for (int i = 0; i < 8; ++i) v[i] = (idx + i < N) ? cnt[idx + i] : 0;
        int run = 0;
#pragma unroll
        for (int i = 0; i < 8; ++i) { run += v[i]; s[i] = run; }
        int x = run;
#pragma unroll
        for (int off = 1; off < 64; off <<= 1) {
            int y = __shfl_up(x, off);
            if (lane >= off) x += y;
        }
        if (lane == 63) wsum[wave] = x;
        __syncthreads();
        if (wave == 0 && lane < 16) {
            int w = wsum[lane];
            int xw = w;
#pragma unroll
            for (int off = 1; off < 16; off <<= 1) {
                int y = __shfl_up(xw, off);
                if (lane >= off) xw += y;
            }
            wsum[lane] = xw - w;   // exclusive over wave totals
        }
        __syncthreads();
        int carry = carry_s;
        int tbase = carry + wsum[wave] + (x - run);
#pragma unroll
        for (int i = 0; i < 8; ++i)
            if (idx + i < N) rp[idx + i] = tbase + s[i] - v[i];
        __syncthreads();
        if (tid == 1023) carry_s = carry + wsum[15] + x;   // + wave15 total
        __syncthreads();
    }
    if (tid == 0) rp[N] = carry_s;
}

__global__ void fill_kernel(const int* __restrict__ src, const int* __restrict__ dst,
                            const int* __restrict__ rp, int* __restrict__ cursor,
                            int* __restrict__ col, int E) {
    int i = blockIdx.x * blockDim.x + threadIdx.x;
    if (i < E) {
        int d = dst[i];
        int pos = rp[d] + atomicAdd(&cursor[d], 1);
        col[pos] = src[i];
    }
}

// ---- dtype prep ------------------------------------------------------------

__global__ void cvt_kernel(const float* __restrict__ X, short* __restrict__ Y, int n) {
    int idx = (blockIdx.x * blockDim.x + threadIdx.x) * 4;
    if (idx < n) {
        float4 v = *reinterpret_cast<const float4*>(X + idx);
        unsigned lo = pack2(v.x, v.y);
        unsigned hi = pack2(v.z, v.w);
        uint2 o; o.x = lo; o.y = hi;
        *reinterpret_cast<uint2*>(Y + idx) = o;
    }
}

// Bt[NO x 128] bf16: rows [0,NWp) = cols of W (zero-padded past NWs),
//                    rows [NWp,NO) = cols of L (zero-padded past NLs)
__global__ void pack_kernel(const float* __restrict__ W, const float* __restrict__ L,
                            short* __restrict__ Bt, int NWs, int NWp, int NLs, int NO) {
    int gid = blockIdx.x * blockDim.x + threadIdx.x;
    if (gid >= NO * 128) return;
    int n = gid >> 7, k = gid & 127;
    float v;
    if (n < NWp) v = (n < NWs) ? W[k * NWs + n] : 0.0f;
    else { int m = n - NWp; v = (m < NLs) ? L[k * NLs + m] : 0.0f; }
    Bt[gid] = f2bf(v);
}

// ---- fused GEMM: [P | R] = A @ [W | L], P scaled by norm_src ---------------
// A: M x 128 bf16. Bt: NO x 128 bf16 (B transposed). One 16-row tile per wave.
// MFMA 16x16x32 layouts: A[row=l&15][k=(l>>4)*8+i], B[k=(l>>4)*8+i][col=l&15],
// C/D col=l&15, row=(l>>4)*4+reg.
template<int NO, int NW, int PPITCH, bool LAYER3>
__global__ __launch_bounds__(256) void mfma_gemm(
    const short* __restrict__ A,
    const short* __restrict__ Bt,
    const float* __restrict__ norm_src,
    const float* __restrict__ bias,
    short* __restrict__ P,
    void* __restrict__ Rout,
    int M)
{
    const int lane = threadIdx.x & 63;
    const int tile = blockIdx.x * 4 + (threadIdx.x >> 6);
    const int row0 = tile << 4;
    if (row0 >= M) return;
    const int lrow = lane & 15;
    const int lk8  = (lane >> 4) << 3;
    const int g4   = (lane >> 4) << 2;

    const short* ap = A + (size_t)(row0 + lrow) * 128 + lk8;
    frag a[4];
#pragma unroll
    for (int ks = 0; ks < 4; ++ks)
        a[ks] = *reinterpret_cast<const frag*>(ap + ks * 32);

    float ns[4];
#pragma unroll
    for (int r = 0; r < 4; ++r) ns[r] = norm_src[row0 + g4 + r];

    constexpr int NT = NO / 16;
#pragma unroll
    for (int nt = 0; nt < NT; ++nt) {
        const short* bp = Bt + (size_t)(nt * 16 + lrow) * 128 + lk8;
        f32x4 acc = {0.f, 0.f, 0.f, 0.f};
#pragma unroll
        for (int ks = 0; ks < 4; ++ks) {
            frag b = *reinterpret_cast<const frag*>(bp + ks * 32);
            acc = __builtin_amdgcn_mfma_f32_16x16x32_bf16(a[ks], b, acc, 0, 0, 0);
        }
        const int c = nt * 16 + lrow;
        if (nt * 16 < NW) {               // P part (norm_src-scaled, bf16)
#pragma unroll
            for (int r = 0; r < 4; ++r) {
                const int orow = row0 + g4 + r;
                if (!LAYER3 || c < 40)
                    P[(size_t)orow * PPITCH + c] = f2bf(acc[r] * ns[r]);
            }
        } else {                          // residual part
            const int oc = c - NW;
#pragma unroll
            for (int r = 0; r < 4; ++r) {
                const int orow = row0 + g4 + r;
                if (LAYER3) {
                    if (oc < 40)
                        ((float*)Rout)[(size_t)orow * 40 + oc] = acc[r] + bias[oc];
                } else {
                    ((short*)Rout)[(size_t)orow * 128 + oc] = f2bf(acc[r]);
                }
            }
        }
    }
}

// ---- aggregation: H[d] = H[d] + norm_dst[d] * sum Pw[col[j]] ---------------

// 128 cols bf16: one wave per node, each lane owns 2 cols (one uint)
__global__ __launch_bounds__(256) void agg128(
    const unsigned* __restrict__ P,      // N x 64 uint
    const int* __restrict__ rp, const int* __restrict__ col,
    const float* __restrict__ norm_dst,
    unsigned* __restrict__ H, int N)     // in-place bf16
{
    int node = blockIdx.x * 4 + (threadIdx.x >> 6);
    if (node >= N) return;
    int lane = threadIdx.x & 63;
    int b = rp[node], e = rp[node + 1];
    float a0 = 0.f, a1 = 0.f;
    int j = b;
    for (; j + 1 < e; j += 2) {
        int s0 = col[j], s1 = col[j + 1];
        unsigned u0 = P[(size_t)s0 * 64 + lane];
        unsigned u1 = P[(size_t)s1 * 64 + lane];
        a0 += bflo(u0) + bflo(u1);
        a1 += bfhi(u0) + bfhi(u1);
    }
    if (j < e) {
        unsigned u = P[(size_t)col[j] * 64 + lane];
        a0 += bflo(u); a1 += bfhi(u);
    }
    float nd = norm_dst[node];
    size_t o = (size_t)node * 64 + lane;
    unsigned r = H[o];
    H[o] = pack2(bflo(r) + nd * a0, bfhi(r) + nd * a1);
}

// 40 cols bf16 gather, fp32 in-place add into d_out
__global__ __launch_bounds__(256) void agg40(
    const short* __restrict__ P,         // N x 40 bf16
    const int* __restrict__ rp, const int* __restrict__ col,
    const float* __restrict__ norm_dst,
    float* __restrict__ OUT, int N)      // N x 40 f32, in-place add
{
    int node = blockIdx.x * 4 + (threadIdx.x >> 6);
    if (node >= N) return;
    int lane = threadIdx.x & 63;
    if (lane >= 40) return;
    int b = rp[node], e = rp[node + 1];
    float a = 0.f;
    for (int j = b; j < e; ++j)
        a += bf2f((unsigned short)P[(size_t)col[j] * 40 + lane]);
    size_t o = (size_t)node * 40 + lane;
    OUT[o] += norm_dst[node] * a;
}

// ---------------------------------------------------------------------------

extern "C" void kernel_launch(void* const* d_in, const int* in_sizes, int n_in,
                              void* d_out, int out_size, void* d_ws, size_t ws_size,
                              hipStream_t stream) {
    const float* feat = (const float*)d_in[0];
    const int*   src  = (const int*)d_in[1];
    const int*   dst  = (const int*)d_in[2];
    const float* W0   = (const float*)d_in[3];
    const float* W1   = (const float*)d_in[4];
    const float* W2   = (const float*)d_in[5];
    const float* b2   = (const float*)d_in[6];
    const float* L0   = (const float*)d_in[7];
    const float* L1   = (const float*)d_in[8];
    const float* L2   = (const float*)d_in[9];
    float* out = (float*)d_out;

    const int E = in_sizes[1];
    const int N = in_sizes[0] / 128;

    // ---- workspace layout ----
    float* fws      = (float*)d_ws;
    float* norm_src = fws;                        // N
    float* norm_dst = fws + N;                    // N
    short* sws      = (short*)(fws + 2 * (size_t)N);
    short* featb    = sws;                        // N*128
    short* hA       = featb + (size_t)N * 128;    // N*128
    short* hB       = hA    + (size_t)N * 128;    // N*128
    short* Pb       = hB    + (size_t)N * 128;    // N*128 (also N*40 for layer 3)
    short* Bt1      = Pb    + (size_t)N * 128;    // 256*128
    short* Bt2      = Bt1 + 256 * 128;            // 256*128
    short* Bt3      = Bt2 + 256 * 128;            // 96*128
    int*   iws      = (int*)(Bt3 + 96 * 128);
    int*   cnt_out  = iws;                        // N
    int*   cnt_in   = iws + N;                    // N
    int*   cursor   = iws + 2 * (size_t)N;        // N
    int*   rp       = iws + 3 * (size_t)N;        // N+1
    int*   col      = rp + N + 1;                 // E

    // ---- preprocessing ----
    hipMemsetAsync(cnt_out, 0, 3 * (size_t)N * sizeof(int), stream);
    deg_kernel<<<(E + 255) / 256, 256, 0, stream>>>(src, dst, cnt_out, cnt_in, E);
    norm_kernel<<<(2 * N + 255) / 256, 256, 0, stream>>>(cnt_out, norm_src, 2 * N);
    scan_kernel<<<1, 1024, 0, stream>>>(cnt_in, rp, N);
    fill_kernel<<<(E + 255) / 256, 256, 0, stream>>>(src, dst, rp, cursor, col, E);

    cvt_kernel<<<((size_t)N * 128 / 4 + 255) / 256, 256, 0, stream>>>(feat, featb, N * 128);
    pack_kernel<<<(256 * 128 + 255) / 256, 256, 0, stream>>>(W0, L0, Bt1, 128, 128, 128, 256);
    pack_kernel<<<(256 * 128 + 255) / 256, 256, 0, stream>>>(W1, L1, Bt2, 128, 128, 128, 256);
    pack_kernel<<<(96 * 128 + 255) / 256, 256, 0, stream>>>(W2, L2, Bt3, 40, 48, 40, 96);

    const int gblocks = ((N / 16) + 3) / 4;       // one 16-row tile per wave
    const int ablocks = (N + 3) / 4;              // one node per wave

    // layer 1
    mfma_gemm<256, 128, 128, false><<<gblocks, 256, 0, stream>>>(
        featb, Bt1, norm_src, nullptr, Pb, hA, N);
    agg128<<<ablocks, 256, 0, stream>>>((const unsigned*)Pb, rp, col, norm_dst, (unsigned*)hA, N);

    // layer 2
    mfma_gemm<256, 128, 128, false><<<gblocks, 256, 0, stream>>>(
        hA, Bt2, norm_src, nullptr, Pb, hB, N);
    agg128<<<ablocks, 256, 0, stream>>>((const unsigned*)Pb, rp, col, norm_dst, (unsigned*)hB, N);

    // layer 3 (residual + bias written straight to d_out in fp32, then agg adds)
    mfma_gemm<96, 48, 40, true><<<gblocks, 256, 0, stream>>>(
        hB, Bt3, norm_src, b2, Pb, out, N);
    agg40<<<ablocks, 256, 0, stream>>>(Pb, rp, col, norm_dst, out, N);
}

// Round 5
// 759.983 us; speedup vs baseline: 9.0070x; 1.0768x over previous
//
#include <hip/hip_runtime.h>

// ---------------------------------------------------------------------------
// GCN round 5: isolation round. Keep swapped-operand MFMA GEMMs + layer-3
// agg-first restructure (both algebra-proven); revert aggregation to the
// round-3-validated serial uint-per-lane gather (with MODE 0/1/2 epilogues).
// ---------------------------------------------------------------------------

using frag  = __attribute__((ext_vector_type(8))) short;   // 8 bf16
using f32x4 = __attribute__((ext_vector_type(4))) float;

static __device__ __forceinline__ short f2bf(float f) {
    union { float f; unsigned u; } x; x.f = f;
    unsigned r = x.u + 0x7FFF + ((x.u >> 16) & 1);         // RNE
    return (short)(r >> 16);
}
static __device__ __forceinline__ float bflo(unsigned u) {
    union { unsigned u; float f; } x; x.u = u << 16; return x.f;
}
static __device__ __forceinline__ float bfhi(unsigned u) {
    union { unsigned u; float f; } x; x.u = u & 0xffff0000u; return x.f;
}
static __device__ __forceinline__ unsigned pack2(float a, float b) {
    return (unsigned)(unsigned short)f2bf(a) | ((unsigned)(unsigned short)f2bf(b) << 16);
}

// ---- graph preprocessing ---------------------------------------------------

__global__ void deg_kernel(const int* __restrict__ src, const int* __restrict__ dst,
                           int* __restrict__ cnt_out, int* __restrict__ cnt_in, int E) {
    int i = blockIdx.x * blockDim.x + threadIdx.x;
    if (i < E) {
        atomicAdd(&cnt_out[src[i]], 1);
        atomicAdd(&cnt_in[dst[i]], 1);
    }
}

__global__ void norm_kernel(const int* __restrict__ cnt, float* __restrict__ norm, int n) {
    int i = blockIdx.x * blockDim.x + threadIdx.x;
    if (i < n) norm[i] = rsqrtf((float)max(cnt[i], 1));
}

__global__ __launch_bounds__(1024) void scan_kernel(const int* __restrict__ cnt,
                                                    int* __restrict__ rp, int N) {
    __shared__ int wsum[16];
    __shared__ int carry_s;
    const int tid = threadIdx.x;
    const int lane = tid & 63, wave = tid >> 6;
    if (tid == 0) carry_s = 0;
    __syncthreads();
    const int CH = 8192;
    for (int base = 0; base < N; base += CH) {
        int idx = base + tid * 8;
        int v[8], s[8];
#pragma unroll
        for (int i = 0; i < 8; ++i) v[i] = (idx + i < N) ? cnt[idx + i] : 0;
        int run = 0;
#pragma unroll
        for (int i = 0; i < 8; ++i) { run += v[i]; s[i] = run; }
        int x = run;
#pragma unroll
        for (int off = 1; off < 64; off <<= 1) {
            int y = __shfl_up(x, off);
            if (lane >= off) x += y;
        }
        if (lane == 63) wsum[wave] = x;
        __syncthreads();
        if (wave == 0 && lane < 16) {
            int w = wsum[lane];
            int xw = w;
#pragma unroll
            for (int off = 1; off < 16; off <<= 1) {
                int y = __shfl_up(xw, off);
                if (lane >= off) xw += y;
            }
            wsum[lane] = xw - w;
        }
        __syncthreads();
        int carry = carry_s;
        int tbase = carry + wsum[wave] + (x - run);
#pragma unroll
        for (int i = 0; i < 8; ++i)
            if (idx + i < N) rp[idx + i] = tbase + s[i] - v[i];
        __syncthreads();
        if (tid == 1023) carry_s = carry + wsum[15] + x;
        __syncthreads();
    }
    if (tid == 0) rp[N] = carry_s;
}

__global__ void fill_kernel(const int* __restrict__ src, const int* __restrict__ dst,
                            const int* __restrict__ rp, int* __restrict__ cursor,
                            int* __restrict__ col, int E) {
    int i = blockIdx.x * blockDim.x + threadIdx.x;
    if (i < E) {
        int d = dst[i];
        int pos = rp[d] + atomicAdd(&cursor[d], 1);
        col[pos] = src[i];
    }
}

// ---- dtype prep ------------------------------------------------------------

__global__ void cvt_kernel(const float* __restrict__ X, short* __restrict__ Y, int n) {
    int idx = (blockIdx.x * blockDim.x + threadIdx.x) * 4;
    if (idx < n) {
        float4 v = *reinterpret_cast<const float4*>(X + idx);
        uint2 o; o.x = pack2(v.x, v.y); o.y = pack2(v.z, v.w);
        *reinterpret_cast<uint2*>(Y + idx) = o;
    }
}

// Bt[256 x 128]: rows 0-127 = cols of W, rows 128-255 = cols of L
__global__ void pack128_kernel(const float* __restrict__ W, const float* __restrict__ L,
                               short* __restrict__ Bt) {
    int gid = blockIdx.x * blockDim.x + threadIdx.x;
    if (gid >= 256 * 128) return;
    int n = gid >> 7, k = gid & 127;
    float v = (n < 128) ? W[k * 128 + n] : L[k * 128 + (n - 128)];
    Bt[gid] = f2bf(v);
}

// Bt3[48 x 256]: Bt3[n][k] = k<128 ? W2[k][n] : L2[k-128][n]; n>=40 -> 0
__global__ void pack_final_kernel(const float* __restrict__ W2, const float* __restrict__ L2,
                                  short* __restrict__ Bt) {
    int gid = blockIdx.x * blockDim.x + threadIdx.x;
    if (gid >= 48 * 256) return;
    int n = gid >> 8, k = gid & 255;
    float v = 0.0f;
    if (n < 40) v = (k < 128) ? W2[k * 40 + n] : L2[(k - 128) * 40 + n];
    Bt[gid] = f2bf(v);
}

// ---- fused GEMM (layers 1,2): [P | R] = A @ [W | L], P scaled by norm_src --
// swapped operands: acc = mfma(b, a) => lane owns row = row0+(l&15),
// cols nt*16 + (l>>4)*4 + j  (4 consecutive -> uint2 store)
__global__ __launch_bounds__(256) void gemm128(
    const short* __restrict__ A,
    const short* __restrict__ Bt,      // 256 x 128
    const float* __restrict__ norm_src,
    short* __restrict__ P,
    short* __restrict__ R,
    int M)
{
    const int lane = threadIdx.x & 63;
    const int wid  = threadIdx.x >> 6;
    const int row0 = (blockIdx.x * 4 + wid) * 32;
    if (row0 >= M) return;
    const int lrow = lane & 15;
    const int lk8  = (lane >> 4) << 3;
    const int g4   = (lane >> 4) << 2;

    const int r0 = row0 + lrow, r1 = row0 + 16 + lrow;
    const int a0r = min(r0, M - 1), a1r = min(r1, M - 1);

    frag a0[4], a1[4];
#pragma unroll
    for (int ks = 0; ks < 4; ++ks) {
        a0[ks] = *reinterpret_cast<const frag*>(A + (size_t)a0r * 128 + lk8 + ks * 32);
        a1[ks] = *reinterpret_cast<const frag*>(A + (size_t)a1r * 128 + lk8 + ks * 32);
    }
    const float ns0 = norm_src[a0r], ns1 = norm_src[a1r];

#pragma unroll
    for (int nt = 0; nt < 16; ++nt) {
        frag b[4];
#pragma unroll
        for (int ks = 0; ks < 4; ++ks)
            b[ks] = *reinterpret_cast<const frag*>(Bt + (size_t)(nt * 16 + lrow) * 128 + lk8 + ks * 32);
        f32x4 acc0 = {0.f, 0.f, 0.f, 0.f};
        f32x4 acc1 = {0.f, 0.f, 0.f, 0.f};
#pragma unroll
        for (int ks = 0; ks < 4; ++ks) {
            acc0 = __builtin_amdgcn_mfma_f32_16x16x32_bf16(b[ks], a0[ks], acc0, 0, 0, 0);
            acc1 = __builtin_amdgcn_mfma_f32_16x16x32_bf16(b[ks], a1[ks], acc1, 0, 0, 0);
        }
        const int cb = nt * 16 + g4;
        if (cb < 128) {
            uint2 p0, p1;
            p0.x = pack2(acc0[0] * ns0, acc0[1] * ns0);
            p0.y = pack2(acc0[2] * ns0, acc0[3] * ns0);
            p1.x = pack2(acc1[0] * ns1, acc1[1] * ns1);
            p1.y = pack2(acc1[2] * ns1, acc1[3] * ns1);
            if (r0 < M) *reinterpret_cast<uint2*>(P + (size_t)r0 * 128 + cb) = p0;
            if (r1 < M) *reinterpret_cast<uint2*>(P + (size_t)r1 * 128 + cb) = p1;
        } else {
            const int oc = cb - 128;
            uint2 p0, p1;
            p0.x = pack2(acc0[0], acc0[1]); p0.y = pack2(acc0[2], acc0[3]);
            p1.x = pack2(acc1[0], acc1[1]); p1.y = pack2(acc1[2], acc1[3]);
            if (r0 < M) *reinterpret_cast<uint2*>(R + (size_t)r0 * 128 + oc) = p0;
            if (r1 < M) *reinterpret_cast<uint2*>(R + (size_t)r1 * 128 + oc) = p1;
        }
    }
}

// ---- final GEMM: out = [m2 | h2] @ Bt3^T + bias  (K=256, 40 fp32 cols) -----
__global__ __launch_bounds__(256) void gemm_final(
    const short* __restrict__ M2,
    const short* __restrict__ H2,
    const short* __restrict__ Bt,      // 48 x 256
    const float* __restrict__ bias,
    float* __restrict__ OUT,
    int M)
{
    const int lane = threadIdx.x & 63;
    const int wid  = threadIdx.x >> 6;
    const int row0 = (blockIdx.x * 4 + wid) * 32;
    if (row0 >= M) return;
    const int lrow = lane & 15;
    const int lk8  = (lane >> 4) << 3;
    const int g4   = (lane >> 4) << 2;

    const int r0 = row0 + lrow, r1 = row0 + 16 + lrow;
    const int a0r = min(r0, M - 1), a1r = min(r1, M - 1);

    frag a0[8], a1[8];
#pragma unroll
    for (int ks = 0; ks < 4; ++ks) {
        a0[ks]     = *reinterpret_cast<const frag*>(M2 + (size_t)a0r * 128 + lk8 + ks * 32);
        a1[ks]     = *reinterpret_cast<const frag*>(M2 + (size_t)a1r * 128 + lk8 + ks * 32);
        a0[ks + 4] = *reinterpret_cast<const frag*>(H2 + (size_t)a0r * 128 + lk8 + ks * 32);
        a1[ks + 4] = *reinterpret_cast<const frag*>(H2 + (size_t)a1r * 128 + lk8 + ks * 32);
    }

#pragma unroll
    for (int nt = 0; nt < 3; ++nt) {
        frag b[8];
#pragma unroll
        for (int ks = 0; ks < 8; ++ks)
            b[ks] = *reinterpret_cast<const frag*>(Bt + (size_t)(nt * 16 + lrow) * 256 + lk8 + ks * 32);
        f32x4 acc0 = {0.f, 0.f, 0.f, 0.f};
        f32x4 acc1 = {0.f, 0.f, 0.f, 0.f};
#pragma unroll
        for (int ks = 0; ks < 8; ++ks) {
            acc0 = __builtin_amdgcn_mfma_f32_16x16x32_bf16(b[ks], a0[ks], acc0, 0, 0, 0);
            acc1 = __builtin_amdgcn_mfma_f32_16x16x32_bf16(b[ks], a1[ks], acc1, 0, 0, 0);
        }
        const int cb = nt * 16 + g4;
        if (cb + 3 < 40) {
            float4 bv = *reinterpret_cast<const float4*>(&bias[cb]);
            if (r0 < M) {
                float4 o = make_float4(acc0[0] + bv.x, acc0[1] + bv.y, acc0[2] + bv.z, acc0[3] + bv.w);
                *reinterpret_cast<float4*>(&OUT[(size_t)r0 * 40 + cb]) = o;
            }
            if (r1 < M) {
                float4 o = make_float4(acc1[0] + bv.x, acc1[1] + bv.y, acc1[2] + bv.z, acc1[3] + bv.w);
                *reinterpret_cast<float4*>(&OUT[(size_t)r1 * 40 + cb]) = o;
            }
        }
    }
}

// ---- aggregation (round-3 validated serial gather, one wave per node) ------
// MODE 0: H += nd * sum             (bf16 in-place)
// MODE 1: H += nd * sum; G = ns*H   (bf16)
// MODE 2: H  = nd * sum             (bf16, pure write)
template<int MODE>
__global__ __launch_bounds__(256) void agg_kernel(
    const unsigned* __restrict__ P,    // N x 64 uints (= N x 128 bf16)
    const int* __restrict__ rp, const int* __restrict__ col,
    const float* __restrict__ norm_dst, const float* __restrict__ norm_src,
    unsigned* __restrict__ H,
    unsigned* __restrict__ G,
    int N)
{
    int node = blockIdx.x * 4 + (threadIdx.x >> 6);
    if (node >= N) return;
    int lane = threadIdx.x & 63;
    int b = rp[node], e = rp[node + 1];
    float a0 = 0.f, a1 = 0.f;
    int j = b;
    for (; j + 1 < e; j += 2) {
        int s0 = col[j], s1 = col[j + 1];
        unsigned u0 = P[(size_t)s0 * 64 + lane];
        unsigned u1 = P[(size_t)s1 * 64 + lane];
        a0 += bflo(u0) + bflo(u1);
        a1 += bfhi(u0) + bfhi(u1);
    }
    if (j < e) {
        unsigned u = P[(size_t)col[j] * 64 + lane];
        a0 += bflo(u); a1 += bfhi(u);
    }
    const float nd = norm_dst[node];
    const size_t o = (size_t)node * 64 + lane;
    if (MODE == 2) {
        H[o] = pack2(nd * a0, nd * a1);
    } else {
        unsigned r = H[o];
        float h0 = bflo(r) + nd * a0;
        float h1 = bfhi(r) + nd * a1;
        H[o] = pack2(h0, h1);
        if (MODE == 1) {
            const float ns = norm_src[node];
            G[o] = pack2(ns * h0, ns * h1);
        }
    }
}

// ---------------------------------------------------------------------------

extern "C" void kernel_launch(void* const* d_in, const int* in_sizes, int n_in,
                              void* d_out, int out_size, void* d_ws, size_t ws_size,
                              hipStream_t stream) {
    const float* feat = (const float*)d_in[0];
    const int*   src  = (const int*)d_in[1];
    const int*   dst  = (const int*)d_in[2];
    const float* W0   = (const float*)d_in[3];
    const float* W1   = (const float*)d_in[4];
    const float* W2   = (const float*)d_in[5];
    const float* b2   = (const float*)d_in[6];
    const float* L0   = (const float*)d_in[7];
    const float* L1   = (const float*)d_in[8];
    const float* L2   = (const float*)d_in[9];
    float* out = (float*)d_out;

    const int E = in_sizes[1];
    const int N = in_sizes[0] / 128;

    // ---- workspace layout ----
    float* fws      = (float*)d_ws;
    float* norm_src = fws;                        // N
    float* norm_dst = fws + N;                    // N
    short* sws      = (short*)(fws + 2 * (size_t)N);
    short* featb    = sws;                        // N*128
    short* bufP     = featb + (size_t)N * 128;    // N*128 (P scratch)
    short* bufA     = bufP  + (size_t)N * 128;    // N*128 (h1, later m2)
    short* bufB     = bufA  + (size_t)N * 128;    // N*128 (h2)
    short* bufC     = bufB  + (size_t)N * 128;    // N*128 (g2)
    short* Bt1      = bufC  + (size_t)N * 128;    // 256*128
    short* Bt2      = Bt1 + 256 * 128;
    short* Bt3      = Bt2 + 256 * 128;            // 48*256
    int*   iws      = (int*)(Bt3 + 48 * 256);
    int*   cnt_out  = iws;                        // N
    int*   cnt_in   = iws + N;                    // N
    int*   cursor   = iws + 2 * (size_t)N;        // N
    int*   rp       = iws + 3 * (size_t)N;        // N+1
    int*   col      = rp + N + 1;                 // E

    // ---- preprocessing ----
    hipMemsetAsync(cnt_out, 0, 3 * (size_t)N * sizeof(int), stream);
    deg_kernel<<<(E + 255) / 256, 256, 0, stream>>>(src, dst, cnt_out, cnt_in, E);
    norm_kernel<<<(2 * N + 255) / 256, 256, 0, stream>>>(cnt_out, norm_src, 2 * N);
    scan_kernel<<<1, 1024, 0, stream>>>(cnt_in, rp, N);
    fill_kernel<<<(E + 255) / 256, 256, 0, stream>>>(src, dst, rp, cursor, col, E);

    cvt_kernel<<<((size_t)N * 128 / 4 + 255) / 256, 256, 0, stream>>>(feat, featb, N * 128);
    pack128_kernel<<<(256 * 128 + 255) / 256, 256, 0, stream>>>(W0, L0, Bt1);
    pack128_kernel<<<(256 * 128 + 255) / 256, 256, 0, stream>>>(W1, L1, Bt2);
    pack_final_kernel<<<(48 * 256 + 255) / 256, 256, 0, stream>>>(W2, L2, Bt3);

    const int gblocks = (N + 127) / 128;          // 32 rows/wave, 4 waves/block
    const int ablocks = (N + 3) / 4;              // one node per wave

    // layer 1: h1 = agg(P1) + R1                                   -> bufA
    gemm128<<<gblocks, 256, 0, stream>>>(featb, Bt1, norm_src, bufP, bufA, N);
    agg_kernel<0><<<ablocks, 256, 0, stream>>>((const unsigned*)bufP, rp, col,
        norm_dst, norm_src, (unsigned*)bufA, nullptr, N);

    // layer 2: h2 = agg(P2) + R2; also emit g2 = norm_src*h2       -> bufB, bufC
    gemm128<<<gblocks, 256, 0, stream>>>(bufA, Bt2, norm_src, bufP, bufB, N);
    agg_kernel<1><<<ablocks, 256, 0, stream>>>((const unsigned*)bufP, rp, col,
        norm_dst, norm_src, (unsigned*)bufB, (unsigned*)bufC, N);

    // layer 3: m2 = norm_dst * sum g2[col];  out = [m2|h2]@[W2;L2] + b2
    agg_kernel<2><<<ablocks, 256, 0, stream>>>((const unsigned*)bufC, rp, col,
        norm_dst, norm_src, (unsigned*)bufA, nullptr, N);
    gemm_final<<<gblocks, 256, 0, stream>>>(bufA, bufB, Bt3, b2, out, N);
}

// Round 6
// 486.406 us; speedup vs baseline: 14.0730x; 1.5624x over previous
//
#include <hip/hip_runtime.h>

// ---------------------------------------------------------------------------
// GCN round 6: slotted CSR (no scan/fill), register edge-lists with shfl
// broadcast, fp32-A fused layer-1 GEMM (no cvt), on-the-fly norm_src in
// layer-3 agg (no g2 buffer). Validated MFMA GEMM + agg bodies unchanged.
// ---------------------------------------------------------------------------

using frag  = __attribute__((ext_vector_type(8))) short;   // 8 bf16
using f32x4 = __attribute__((ext_vector_type(4))) float;

static __device__ __forceinline__ short f2bf(float f) {
    union { float f; unsigned u; } x; x.f = f;
    unsigned r = x.u + 0x7FFF + ((x.u >> 16) & 1);         // RNE
    return (short)(r >> 16);
}
static __device__ __forceinline__ float bflo(unsigned u) {
    union { unsigned u; float f; } x; x.u = u << 16; return x.f;
}
static __device__ __forceinline__ float bfhi(unsigned u) {
    union { unsigned u; float f; } x; x.u = u & 0xffff0000u; return x.f;
}
static __device__ __forceinline__ unsigned pack2(float a, float b) {
    return (unsigned)(unsigned short)f2bf(a) | ((unsigned)(unsigned short)f2bf(b) << 16);
}

// ---- graph build: histograms + slotted CSR in one pass ---------------------
// cnt_in doubles as the slot cursor; after the kernel it holds in-degree.
__global__ void build_kernel(const int* __restrict__ src, const int* __restrict__ dst,
                             int* __restrict__ cnt_out, int* __restrict__ cnt_in,
                             int* __restrict__ slot, int E) {
    int i = blockIdx.x * blockDim.x + threadIdx.x;
    if (i < E) {
        int s = src[i], d = dst[i];
        atomicAdd(&cnt_out[s], 1);
        int pos = atomicAdd(&cnt_in[d], 1);
        if (pos < 64) slot[((size_t)d << 6) + pos] = s;     // MAXDEG=64
    }
}

// norm_src[i] = rsqrt(max(out_deg,1))
__global__ void norm_kernel(const int* __restrict__ cnt, float* __restrict__ norm, int n) {
    int i = blockIdx.x * blockDim.x + threadIdx.x;
    if (i < n) norm[i] = rsqrtf((float)max(cnt[i], 1));
}

// ---- weight packing --------------------------------------------------------

// Bt[256 x 128]: rows 0-127 = cols of W, rows 128-255 = cols of L
__global__ void pack128_kernel(const float* __restrict__ W, const float* __restrict__ L,
                               short* __restrict__ Bt) {
    int gid = blockIdx.x * blockDim.x + threadIdx.x;
    if (gid >= 256 * 128) return;
    int n = gid >> 7, k = gid & 127;
    float v = (n < 128) ? W[k * 128 + n] : L[k * 128 + (n - 128)];
    Bt[gid] = f2bf(v);
}

// Bt3[48 x 256]: Bt3[n][k] = k<128 ? W2[k][n] : L2[k-128][n]; n>=40 -> 0
__global__ void pack_final_kernel(const float* __restrict__ W2, const float* __restrict__ L2,
                                  short* __restrict__ Bt) {
    int gid = blockIdx.x * blockDim.x + threadIdx.x;
    if (gid >= 48 * 256) return;
    int n = gid >> 8, k = gid & 255;
    float v = 0.0f;
    if (n < 40) v = (k < 128) ? W2[k * 40 + n] : L2[(k - 128) * 40 + n];
    Bt[gid] = f2bf(v);
}

// ---- fused GEMM (layers 1,2): [P | R] = A @ [W | L], P scaled by norm_src --
// swapped operands: acc = mfma(b, a) => lane owns row = row0+(l&15),
// cols nt*16 + (l>>4)*4 + j  (4 consecutive -> uint2 store). Validated r5.
static __device__ __forceinline__ frag load_frag_f32(const float* p) {
    float4 f0 = *reinterpret_cast<const float4*>(p);
    float4 f1 = *reinterpret_cast<const float4*>(p + 4);
    union { frag f; unsigned u[4]; } t;
    t.u[0] = pack2(f0.x, f0.y); t.u[1] = pack2(f0.z, f0.w);
    t.u[2] = pack2(f1.x, f1.y); t.u[3] = pack2(f1.z, f1.w);
    return t.f;
}

template<bool AF32>
__global__ __launch_bounds__(256) void gemm128(
    const void* __restrict__ A,        // M x 128 (fp32 if AF32 else bf16)
    const short* __restrict__ Bt,      // 256 x 128 bf16
    const float* __restrict__ norm_src,
    short* __restrict__ P,
    short* __restrict__ R,
    int M)
{
    const int lane = threadIdx.x & 63;
    const int wid  = threadIdx.x >> 6;
    const int row0 = (blockIdx.x * 4 + wid) * 32;
    if (row0 >= M) return;
    const int lrow = lane & 15;
    const int lk8  = (lane >> 4) << 3;
    const int g4   = (lane >> 4) << 2;

    const int r0 = row0 + lrow, r1 = row0 + 16 + lrow;
    const int a0r = min(r0, M - 1), a1r = min(r1, M - 1);

    frag a0[4], a1[4];
#pragma unroll
    for (int ks = 0; ks < 4; ++ks) {
        if (AF32) {
            const float* Af = (const float*)A;
            a0[ks] = load_frag_f32(Af + (size_t)a0r * 128 + lk8 + ks * 32);
            a1[ks] = load_frag_f32(Af + (size_t)a1r * 128 + lk8 + ks * 32);
        } else {
            const short* Ab = (const short*)A;
            a0[ks] = *reinterpret_cast<const frag*>(Ab + (size_t)a0r * 128 + lk8 + ks * 32);
            a1[ks] = *reinterpret_cast<const frag*>(Ab + (size_t)a1r * 128 + lk8 + ks * 32);
        }
    }
    const float ns0 = norm_src[a0r], ns1 = norm_src[a1r];

#pragma unroll
    for (int nt = 0; nt < 16; ++nt) {
        frag b[4];
#pragma unroll
        for (int ks = 0; ks < 4; ++ks)
            b[ks] = *reinterpret_cast<const frag*>(Bt + (size_t)(nt * 16 + lrow) * 128 + lk8 + ks * 32);
        f32x4 acc0 = {0.f, 0.f, 0.f, 0.f};
        f32x4 acc1 = {0.f, 0.f, 0.f, 0.f};
#pragma unroll
        for (int ks = 0; ks < 4; ++ks) {
            acc0 = __builtin_amdgcn_mfma_f32_16x16x32_bf16(b[ks], a0[ks], acc0, 0, 0, 0);
            acc1 = __builtin_amdgcn_mfma_f32_16x16x32_bf16(b[ks], a1[ks], acc1, 0, 0, 0);
        }
        const int cb = nt * 16 + g4;
        if (cb < 128) {
            uint2 p0, p1;
            p0.x = pack2(acc0[0] * ns0, acc0[1] * ns0);
            p0.y = pack2(acc0[2] * ns0, acc0[3] * ns0);
            p1.x = pack2(acc1[0] * ns1, acc1[1] * ns1);
            p1.y = pack2(acc1[2] * ns1, acc1[3] * ns1);
            if (r0 < M) *reinterpret_cast<uint2*>(P + (size_t)r0 * 128 + cb) = p0;
            if (r1 < M) *reinterpret_cast<uint2*>(P + (size_t)r1 * 128 + cb) = p1;
        } else {
            const int oc = cb - 128;
            uint2 p0, p1;
            p0.x = pack2(acc0[0], acc0[1]); p0.y = pack2(acc0[2], acc0[3]);
            p1.x = pack2(acc1[0], acc1[1]); p1.y = pack2(acc1[2], acc1[3]);
            if (r0 < M) *reinterpret_cast<uint2*>(R + (size_t)r0 * 128 + oc) = p0;
            if (r1 < M) *reinterpret_cast<uint2*>(R + (size_t)r1 * 128 + oc) = p1;
        }
    }
}

// ---- final GEMM: out = [m2 | h2] @ Bt3^T + bias  (K=256, 40 fp32 cols) -----
__global__ __launch_bounds__(256) void gemm_final(
    const short* __restrict__ M2,
    const short* __restrict__ H2,
    const short* __restrict__ Bt,      // 48 x 256
    const float* __restrict__ bias,
    float* __restrict__ OUT,
    int M)
{
    const int lane = threadIdx.x & 63;
    const int wid  = threadIdx.x >> 6;
    const int row0 = (blockIdx.x * 4 + wid) * 32;
    if (row0 >= M) return;
    const int lrow = lane & 15;
    const int lk8  = (lane >> 4) << 3;
    const int g4   = (lane >> 4) << 2;

    const int r0 = row0 + lrow, r1 = row0 + 16 + lrow;
    const int a0r = min(r0, M - 1), a1r = min(r1, M - 1);

    frag a0[8], a1[8];
#pragma unroll
    for (int ks = 0; ks < 4; ++ks) {
        a0[ks]     = *reinterpret_cast<const frag*>(M2 + (size_t)a0r * 128 + lk8 + ks * 32);
        a1[ks]     = *reinterpret_cast<const frag*>(M2 + (size_t)a1r * 128 + lk8 + ks * 32);
        a0[ks + 4] = *reinterpret_cast<const frag*>(H2 + (size_t)a0r * 128 + lk8 + ks * 32);
        a1[ks + 4] = *reinterpret_cast<const frag*>(H2 + (size_t)a1r * 128 + lk8 + ks * 32);
    }

#pragma unroll
    for (int nt = 0; nt < 3; ++nt) {
        frag b[8];
#pragma unroll
        for (int ks = 0; ks < 8; ++ks)
            b[ks] = *reinterpret_cast<const frag*>(Bt + (size_t)(nt * 16 + lrow) * 256 + lk8 + ks * 32);
        f32x4 acc0 = {0.f, 0.f, 0.f, 0.f};
        f32x4 acc1 = {0.f, 0.f, 0.f, 0.f};
#pragma unroll
        for (int ks = 0; ks < 8; ++ks) {
            acc0 = __builtin_amdgcn_mfma_f32_16x16x32_bf16(b[ks], a0[ks], acc0, 0, 0, 0);
            acc1 = __builtin_amdgcn_mfma_f32_16x16x32_bf16(b[ks], a1[ks], acc1, 0, 0, 0);
        }
        const int cb = nt * 16 + g4;
        if (cb + 3 < 40) {
            float4 bv = *reinterpret_cast<const float4*>(&bias[cb]);
            if (r0 < M) {
                float4 o = make_float4(acc0[0] + bv.x, acc0[1] + bv.y, acc0[2] + bv.z, acc0[3] + bv.w);
                *reinterpret_cast<float4*>(&OUT[(size_t)r0 * 40 + cb]) = o;
            }
            if (r1 < M) {
                float4 o = make_float4(acc1[0] + bv.x, acc1[1] + bv.y, acc1[2] + bv.z, acc1[3] + bv.w);
                *reinterpret_cast<float4*>(&OUT[(size_t)r1 * 40 + cb]) = o;
            }
        }
    }
}

// ---- aggregation: one wave per node; edge list in registers ----------------
// MODE 0: H += nd * sum P[s]                       (bf16 in-place)
// MODE 2: H  = nd * sum norm_src[s] * P[s]         (bf16, pure write)
template<int MODE>
__global__ __launch_bounds__(256) void agg_kernel(
    const unsigned* __restrict__ P,    // N x 64 uints (= N x 128 bf16)
    const int* __restrict__ cnt_in,
    const int* __restrict__ slot,      // N x 64
    const float* __restrict__ norm_src,
    unsigned* __restrict__ H,
    int N)
{
    int node = blockIdx.x * 4 + (threadIdx.x >> 6);
    if (node >= N) return;
    int lane = threadIdx.x & 63;
    const int cnt = cnt_in[node];
    const int c = min(cnt, 64);
    const size_t base = (size_t)node << 6;
    int cv = (lane < c) ? slot[base + lane] : 0;

    float a0 = 0.f, a1 = 0.f;
    int j = 0;
    for (; j + 1 < c; j += 2) {
        int s0 = __shfl(cv, j), s1 = __shfl(cv, j + 1);
        unsigned u0 = P[(size_t)s0 * 64 + lane];
        unsigned u1 = P[(size_t)s1 * 64 + lane];
        if (MODE == 2) {
            float f0 = norm_src[s0], f1 = norm_src[s1];
            a0 += f0 * bflo(u0) + f1 * bflo(u1);
            a1 += f0 * bfhi(u0) + f1 * bfhi(u1);
        } else {
            a0 += bflo(u0) + bflo(u1);
            a1 += bfhi(u0) + bfhi(u1);
        }
    }
    if (j < c) {
        int s = __shfl(cv, j);
        unsigned u = P[(size_t)s * 64 + lane];
        if (MODE == 2) {
            float f = norm_src[s];
            a0 += f * bflo(u); a1 += f * bfhi(u);
        } else {
            a0 += bflo(u); a1 += bfhi(u);
        }
    }
    const float nd = rsqrtf((float)max(cnt, 1));
    const size_t o = base + lane;
    if (MODE == 2) {
        H[o] = pack2(nd * a0, nd * a1);
    } else {
        unsigned r = H[o];
        H[o] = pack2(bflo(r) + nd * a0, bfhi(r) + nd * a1);
    }
}

// ---------------------------------------------------------------------------

extern "C" void kernel_launch(void* const* d_in, const int* in_sizes, int n_in,
                              void* d_out, int out_size, void* d_ws, size_t ws_size,
                              hipStream_t stream) {
    const float* feat = (const float*)d_in[0];
    const int*   src  = (const int*)d_in[1];
    const int*   dst  = (const int*)d_in[2];
    const float* W0   = (const float*)d_in[3];
    const float* W1   = (const float*)d_in[4];
    const float* W2   = (const float*)d_in[5];
    const float* b2   = (const float*)d_in[6];
    const float* L0   = (const float*)d_in[7];
    const float* L1   = (const float*)d_in[8];
    const float* L2   = (const float*)d_in[9];
    float* out = (float*)d_out;

    const int E = in_sizes[1];
    const int N = in_sizes[0] / 128;

    // ---- workspace layout ----
    float* fws      = (float*)d_ws;
    float* norm_src = fws;                        // N
    short* sws      = (short*)(fws + N);
    short* bufP     = sws;                        // N*128 (P scratch)
    short* bufA     = bufP + (size_t)N * 128;     // N*128 (h1, later m2)
    short* bufB     = bufA + (size_t)N * 128;     // N*128 (h2)
    short* Bt1      = bufB + (size_t)N * 128;     // 256*128
    short* Bt2      = Bt1 + 256 * 128;
    short* Bt3      = Bt2 + 256 * 128;            // 48*256
    int*   iws      = (int*)(Bt3 + 48 * 256);
    int*   cnt_out  = iws;                        // N
    int*   cnt_in   = iws + N;                    // N (doubles as slot cursor)
    int*   slot     = iws + 2 * (size_t)N;        // N*64

    // ---- graph build ----
    hipMemsetAsync(cnt_out, 0, 2 * (size_t)N * sizeof(int), stream);
    build_kernel<<<(E + 255) / 256, 256, 0, stream>>>(src, dst, cnt_out, cnt_in, slot, E);
    norm_kernel<<<(N + 255) / 256, 256, 0, stream>>>(cnt_out, norm_src, N);

    pack128_kernel<<<(256 * 128 + 255) / 256, 256, 0, stream>>>(W0, L0, Bt1);
    pack128_kernel<<<(256 * 128 + 255) / 256, 256, 0, stream>>>(W1, L1, Bt2);
    pack_final_kernel<<<(48 * 256 + 255) / 256, 256, 0, stream>>>(W2, L2, Bt3);

    const int gblocks = (N + 127) / 128;          // 32 rows/wave, 4 waves/block
    const int ablocks = (N + 3) / 4;              // one node per wave

    // layer 1: h1 = agg(P1) + R1                                   -> bufA
    gemm128<true><<<gblocks, 256, 0, stream>>>(feat, Bt1, norm_src, bufP, bufA, N);
    agg_kernel<0><<<ablocks, 256, 0, stream>>>((const unsigned*)bufP, cnt_in, slot,
        nullptr, (unsigned*)bufA, N);

    // layer 2: h2 = agg(P2) + R2                                   -> bufB
    gemm128<false><<<gblocks, 256, 0, stream>>>(bufA, Bt2, norm_src, bufP, bufB, N);
    agg_kernel<0><<<ablocks, 256, 0, stream>>>((const unsigned*)bufP, cnt_in, slot,
        nullptr, (unsigned*)bufB, N);

    // layer 3: m2 = nd * sum ns[s]*h2[s]  -> bufA;  out = [m2|h2]@Bt3 + b2
    agg_kernel<2><<<ablocks, 256, 0, stream>>>((const unsigned*)bufB, cnt_in, slot,
        norm_src, (unsigned*)bufA, N);
    gemm_final<<<gblocks, 256, 0, stream>>>(bufA, bufB, Bt3, b2, out, N);
}